// Round 5
// baseline (1170.192 us; speedup 1.0000x reference)
//
#include <hip/hip_runtime.h>

// GCN: out = prelu(GCNConv2(prelu(GCNConv1(x)))), proj = MLP(out)
// R5: agg128 edge loop unrolled 12-wide (latency -> 12 gathers in flight).
// R8: weights fragment-contiguous; operand-swapped MFMA; coalesced C stores.
// R9: gemmL: B staged ONCE into LDS (full N x K, 64-128KB), 8-wave blocks
//     cover ALL columns -> A read exactly once across the grid (was 2-4x).
//     Waves read B frags from LDS (conflict-free 1KB ds_read_b128), 256
//     blocks grid-stride over 128-row tiles, no barriers in main loop.

typedef __attribute__((ext_vector_type(4))) float  f32x4;
typedef __attribute__((ext_vector_type(8))) __bf16 bf16x8;
typedef __attribute__((ext_vector_type(8))) short  short8;

__device__ __forceinline__ bf16x8 as_bf(short8 s) {
    union { short8 s; bf16x8 b; } u; u.s = s; return u.b;
}

// truncation split: x = hi + lo + eps, |eps| <= 2^-16 |x|
__device__ __forceinline__ short2 split1(float x) {
    unsigned u = __float_as_uint(x);
    short hi = (short)(u >> 16);
    float hif = __uint_as_float(u & 0xFFFF0000u);
    short lo = (short)(__float_as_uint(x - hif) >> 16);
    return make_short2(hi, lo);
}

// ---------------- degree count ----------------
__global__ void deg_kernel(const int* __restrict__ dst, int* __restrict__ deg, int E) {
    int e = blockIdx.x * blockDim.x + threadIdx.x;
    if (e < E) atomicAdd(&deg[dst[e]], 1);
}

// ---------------- scan phase 1: per-block (1024 elems) sum + dinv ----------------
__global__ __launch_bounds__(256)
void part_kernel(const int* __restrict__ deg, int* __restrict__ bsum,
                 float* __restrict__ dinv, int n) {
    int tid = threadIdx.x;
    int base = blockIdx.x * 1024 + tid * 4;
    int d[4] = {0, 0, 0, 0};
    if (base + 3 < n) {
        int4 v = *(const int4*)(deg + base);
        d[0] = v.x; d[1] = v.y; d[2] = v.z; d[3] = v.w;
    } else {
        for (int j = 0; j < 4; ++j) if (base + j < n) d[j] = deg[base + j];
    }
    for (int j = 0; j < 4; ++j)
        if (base + j < n) dinv[base + j] = rsqrtf((float)(d[j] + 1));
    int s = d[0] + d[1] + d[2] + d[3];
    for (int off = 32; off > 0; off >>= 1) s += __shfl_down(s, off);
    __shared__ int wsum[4];
    if ((tid & 63) == 0) wsum[tid >> 6] = s;
    __syncthreads();
    if (tid == 0) bsum[blockIdx.x] = wsum[0] + wsum[1] + wsum[2] + wsum[3];
}

// ---------------- scan phase 2: single block over block sums ----------------
__global__ __launch_bounds__(1024)
void topscan_kernel(const int* __restrict__ bsum, int* __restrict__ bbase, int nb) {
    __shared__ int sh[1024];
    int tid = threadIdx.x;
    int own = (tid < nb) ? bsum[tid] : 0;
    sh[tid] = own;
    __syncthreads();
    for (int off = 1; off < 1024; off <<= 1) {
        int t = (tid >= off) ? sh[tid - off] : 0;
        __syncthreads();
        sh[tid] += t;
        __syncthreads();
    }
    if (tid < nb) bbase[tid] = sh[tid] - own;   // exclusive
}

// ---------------- scan phase 3: per-block local scan + base -> offsets ----------------
__global__ __launch_bounds__(256)
void offs_kernel(const int* __restrict__ deg, const int* __restrict__ bbase,
                 int* __restrict__ offsets, int n) {
    int tid = threadIdx.x;
    int base = blockIdx.x * 1024 + tid * 4;
    int d[4] = {0, 0, 0, 0};
    if (base + 3 < n) {
        int4 v = *(const int4*)(deg + base);
        d[0] = v.x; d[1] = v.y; d[2] = v.z; d[3] = v.w;
    } else {
        for (int j = 0; j < 4; ++j) if (base + j < n) d[j] = deg[base + j];
    }
    int s = d[0] + d[1] + d[2] + d[3];
    __shared__ int sh[256];
    sh[tid] = s;
    __syncthreads();
    for (int off = 1; off < 256; off <<= 1) {
        int t = (tid >= off) ? sh[tid - off] : 0;
        __syncthreads();
        sh[tid] += t;
        __syncthreads();
    }
    int run = bbase[blockIdx.x] + sh[tid] - s;   // exclusive prefix for this thread
    for (int j = 0; j < 4; ++j) {
        int idx = base + j;
        if (idx <= n) offsets[idx] = run;        // also writes offsets[n]
        if (idx < n) run += d[j];
    }
}

// ---------------- CSR fill ----------------
__global__ void fill_kernel(const int* __restrict__ src, const int* __restrict__ dst,
                            const int* __restrict__ offsets, int* __restrict__ cursor,
                            int* __restrict__ csr, int E) {
    int e = blockIdx.x * blockDim.x + threadIdx.x;
    if (e < E) {
        int d = dst[e];
        int pos = offsets[d] + atomicAdd(&cursor[d], 1);
        csr[pos] = src[e];
    }
}

// ---- weight convert: W[K][N] fp32 -> fragment-contiguous bf16 hi/lo planes ----
// elem o = ((nt*KT + kt)*64 + quad*16 + l16)*8 + j  <->  col nt*16+l16,
// k = kt*32 + quad*8 + j. Wave frag load = one contiguous 1KB block.
__global__ void wconv_kernel(const float* __restrict__ W, short* __restrict__ Fh,
                             short* __restrict__ Fl, int K, int N, int ktlog) {
    int o = blockIdx.x * blockDim.x + threadIdx.x;
    if (o >= K * N) return;
    int j  = o & 7;
    int l  = (o >> 3) & 15;
    int q  = (o >> 7) & 3;
    int t2 = o >> 9;
    int kt = t2 & ((1 << ktlog) - 1);
    int nt = t2 >> ktlog;
    int nn = nt * 16 + l;
    int kk = kt * 32 + q * 8 + j;
    short2 s = split1(W[(size_t)kk * N + nn]);
    Fh[o] = s.x;
    Fl[o] = s.y;
}

// ---------------- aggregation over dim-128 rows, 1 wave per node ----------------
// out[v] = epi( dinv[v] * ( dinv[v]*g[v] + sum_{s->v} dinv[s]*g[s] ) )
// Edge loop 12-wide: 12 independent 512B row-gathers in flight per wave.
__global__ __launch_bounds__(256)
void agg128_kernel(const float* __restrict__ g, const int* __restrict__ csr,
                   const int* __restrict__ offsets, const float* __restrict__ dinv,
                   const float* __restrict__ bias, const float* __restrict__ a_ptr,
                   float* __restrict__ out, int n) {
    int w = threadIdx.x >> 6;
    int lane = threadIdx.x & 63;
    int v = blockIdx.x * 4 + w;
    if (v >= n) return;
    const char* gb = (const char*)g;          // 32-bit voffset form (51.2 MB buffer)
    unsigned loff = (unsigned)lane * 8u;
    float dv = dinv[v];
    float2 self = *(const float2*)(gb + ((unsigned)v * 512u + loff));
    float accx = dv * self.x;
    float accy = dv * self.y;
    int e = offsets[v], end = offsets[v + 1];
#pragma unroll 1
    for (; e < end; e += 12) {
        int   idx[12];
        float dd[12];
        float2 mm[12];
#pragma unroll
        for (int j = 0; j < 12; ++j) {
            int ee = e + j;
            idx[j] = csr[ee < end ? ee : end - 1];   // clamped dup -> cache hit
        }
#pragma unroll
        for (int j = 0; j < 12; ++j)
            dd[j] = (e + j < end) ? dinv[idx[j]] : 0.f;
#pragma unroll
        for (int j = 0; j < 12; ++j)
            mm[j] = *(const float2*)(gb + ((unsigned)idx[j] * 512u + loff));
#pragma unroll
        for (int j = 0; j < 12; ++j) {
            accx += dd[j] * mm[j].x;
            accy += dd[j] * mm[j].y;
        }
    }
    accx *= dv;
    accy *= dv;
    if (bias) {
        float a = *a_ptr;
        float2 bb = ((const float2*)bias)[lane];
        accx += bb.x;
        accy += bb.y;
        accx = accx >= 0.f ? accx : a * accx;
        accy = accy >= 0.f ? accy : a * accy;
    }
    float2 r; r.x = accx; r.y = accy;
    ((float2*)out)[(size_t)v * 64 + lane] = r;
}

// ---------------- split-bf16 MFMA GEMM, B LDS-resident, full-width blocks ----
// C[M][N=NT*16] = epi( A[M][K=KT*32] @ B + bias ). 512 thr = 8 waves x 16 rows
// = 128-row tiles, grid-stride. B (hi+lo planes, frag-contiguous) staged once
// to LDS; waves ds_read_b128 fragments (each lane a distinct 16B -> no
// conflicts). A rows read exactly once across grid. No barriers in main loop.
template<int KT, int NT>
__global__ __launch_bounds__(512)
void gemmL_kernel(const float* __restrict__ A,
                  const short* __restrict__ Bh, const short* __restrict__ Bl,
                  float* __restrict__ C, int M, int ntiles,
                  const float* __restrict__ bias, int act,
                  const float* __restrict__ a_ptr) {
    constexpr int N = NT * 16;
    __shared__ short lh[NT * KT * 512];
    __shared__ short ll[NT * KT * 512];

    const int tid  = threadIdx.x;
    const int wave = tid >> 6, lane = tid & 63;
    const int quad = lane >> 4, l16 = lane & 15;

    // stage B planes (coalesced short8 copies)
    constexpr int units = NT * KT * 64;          // short8 units per plane
    for (int i = tid; i < units; i += 512) {
        ((short8*)lh)[i] = ((const short8*)Bh)[i];
        ((short8*)ll)[i] = ((const short8*)Bl)[i];
    }
    __syncthreads();

    const float aw = (act == 2) ? *a_ptr : 0.f;

#pragma unroll 1
    for (int tile = blockIdx.x; tile < ntiles; tile += gridDim.x) {
        const int m  = tile * 128 + wave * 16 + l16;
        const int mc = m < M ? m : M - 1;
        const float* Ap = A + (size_t)mc * (KT * 32) + quad * 8;

        f32x4 acc[NT];
#pragma unroll
        for (int t = 0; t < NT; ++t) acc[t] = (f32x4){0.f, 0.f, 0.f, 0.f};

#pragma unroll
        for (int kh = 0; kh < KT / 4; ++kh) {
            float4 av[8];
#pragma unroll
            for (int kk = 0; kk < 4; ++kk) {
                av[2 * kk]     = *(const float4*)(Ap + (kh * 4 + kk) * 32);
                av[2 * kk + 1] = *(const float4*)(Ap + (kh * 4 + kk) * 32 + 4);
            }
#pragma unroll
            for (int kk = 0; kk < 4; ++kk) {
                const int kt = kh * 4 + kk;
                float4 v0 = av[2 * kk], v1 = av[2 * kk + 1];
                short8 ah, al;
                short2 s;
                s = split1(v0.x); ah[0] = s.x; al[0] = s.y;
                s = split1(v0.y); ah[1] = s.x; al[1] = s.y;
                s = split1(v0.z); ah[2] = s.x; al[2] = s.y;
                s = split1(v0.w); ah[3] = s.x; al[3] = s.y;
                s = split1(v1.x); ah[4] = s.x; al[4] = s.y;
                s = split1(v1.y); ah[5] = s.x; al[5] = s.y;
                s = split1(v1.z); ah[6] = s.x; al[6] = s.y;
                s = split1(v1.w); ah[7] = s.x; al[7] = s.y;
                bf16x8 a_hi = as_bf(ah), a_lo = as_bf(al);
#pragma unroll
                for (int t = 0; t < NT; ++t) {
                    const int fo = ((t * KT + kt) << 9) + (lane << 3);
                    bf16x8 bh = as_bf(*(const short8*)(lh + fo));
                    bf16x8 bl = as_bf(*(const short8*)(ll + fo));
                    acc[t] = __builtin_amdgcn_mfma_f32_16x16x32_bf16(bh, a_hi, acc[t], 0, 0, 0);
                    acc[t] = __builtin_amdgcn_mfma_f32_16x16x32_bf16(bl, a_hi, acc[t], 0, 0, 0);
                    acc[t] = __builtin_amdgcn_mfma_f32_16x16x32_bf16(bh, a_lo, acc[t], 0, 0, 0);
                }
            }
        }

        if (m < M) {
            float* Crow = C + (size_t)m * N + quad * 4;
#pragma unroll
            for (int t = 0; t < NT; ++t) {
                float4 v;
                v.x = acc[t][0]; v.y = acc[t][1]; v.z = acc[t][2]; v.w = acc[t][3];
                if (bias) {
                    const float4 bb = *(const float4*)(bias + t * 16 + quad * 4);
                    v.x += bb.x; v.y += bb.y; v.z += bb.z; v.w += bb.w;
                }
                if (act == 1) {
                    v.x = fmaxf(v.x, 0.f); v.y = fmaxf(v.y, 0.f);
                    v.z = fmaxf(v.z, 0.f); v.w = fmaxf(v.w, 0.f);
                } else if (act == 2) {
                    v.x = v.x >= 0.f ? v.x : aw * v.x;
                    v.y = v.y >= 0.f ? v.y : aw * v.y;
                    v.z = v.z >= 0.f ? v.z : aw * v.z;
                    v.w = v.w >= 0.f ? v.w : aw * v.w;
                }
                *(float4*)(Crow + t * 16) = v;
            }
        }
    }
}

extern "C" void kernel_launch(void* const* d_in, const int* in_sizes, int n_in,
                              void* d_out, int out_size, void* d_ws, size_t ws_size,
                              hipStream_t stream) {
    const float* x     = (const float*)d_in[0];
    const int*   ei    = (const int*)d_in[1];   // harness materializes int64 as int32
    const float* W1    = (const float*)d_in[2];
    const float* b1    = (const float*)d_in[3];
    const float* W2    = (const float*)d_in[4];
    const float* b2    = (const float*)d_in[5];
    const float* a_ptr = (const float*)d_in[6];
    const float* fc1_w = (const float*)d_in[7];
    const float* fc1_b = (const float*)d_in[8];
    const float* fc2_w = (const float*)d_in[9];
    const float* fc2_b = (const float*)d_in[10];

    const int n = in_sizes[0] / 128;
    const int E = in_sizes[1] / 2;
    const int* src = ei;
    const int* dst = ei + E;
    const int nb = (n + 1023) >> 10;            // scan blocks (98 for n=100000)

    float* out_final  = (float*)d_out;                    // [n,128]
    float* proj_final = out_final + (size_t)n * 128;      // [n,128]
    float* out1       = (float*)d_out;                    // [n,256] transient

    // workspace carve-out (~59.6 MB total)
    char* p = (char*)d_ws;
    auto take = [&](size_t bytes) -> char* {
        char* q = p;
        p += (bytes + 1023) & ~(size_t)1023;
        return q;
    };
    int*   deg     = (int*)take((size_t)n * 4);
    int*   offsets = (int*)take(((size_t)n + 1) * 4);
    int*   cursor  = (int*)take((size_t)n * 4);
    float* dinv    = (float*)take((size_t)n * 4);
    int*   bsum    = (int*)take((size_t)1024 * 4);
    int*   bbase   = (int*)take((size_t)1024 * 4);
    int*   csr     = (int*)take((size_t)E * 4);
    short* W1t_hi  = (short*)take((size_t)256 * 128 * 2);
    short* W1t_lo  = (short*)take((size_t)256 * 128 * 2);
    short* W2t_hi  = (short*)take((size_t)128 * 256 * 2);
    short* W2t_lo  = (short*)take((size_t)128 * 256 * 2);
    short* f1t_hi  = (short*)take((size_t)128 * 128 * 2);
    short* f1t_lo  = (short*)take((size_t)128 * 128 * 2);
    short* f2t_hi  = (short*)take((size_t)128 * 128 * 2);
    short* f2t_lo  = (short*)take((size_t)128 * 128 * 2);
    float* bufA    = (float*)take((size_t)n * 128 * 4);   // [n,128] f32 scratch

    (void)hipMemsetAsync(deg, 0, (size_t)n * 4, stream);
    (void)hipMemsetAsync(cursor, 0, (size_t)n * 4, stream);

    // ---- weight pre-transpose/split into fragment order (tiny) ----
    wconv_kernel<<<(128 * 256 + 255) / 256, 256, 0, stream>>>(W1, W1t_hi, W1t_lo, 128, 256, 2);
    wconv_kernel<<<(256 * 128 + 255) / 256, 256, 0, stream>>>(W2, W2t_hi, W2t_lo, 256, 128, 3);
    wconv_kernel<<<(128 * 128 + 255) / 256, 256, 0, stream>>>(fc1_w, f1t_hi, f1t_lo, 128, 128, 2);
    wconv_kernel<<<(128 * 128 + 255) / 256, 256, 0, stream>>>(fc2_w, f2t_hi, f2t_lo, 128, 128, 2);

    // ---- CSR build (shared by both conv layers) ----
    deg_kernel<<<(E + 255) / 256, 256, 0, stream>>>(dst, deg, E);
    part_kernel<<<nb, 256, 0, stream>>>(deg, bsum, dinv, n);
    topscan_kernel<<<1, 1024, 0, stream>>>(bsum, bbase, nb);
    offs_kernel<<<nb, 256, 0, stream>>>(deg, bbase, offsets, n);
    fill_kernel<<<(E + 255) / 256, 256, 0, stream>>>(src, dst, offsets, cursor, csr, E);

    const int ntiles = (n + 127) / 128;         // 128-row tiles (782)

    // ---- layer 1: aggregate first (dim 128): aggx = A_hat x -> bufA
    agg128_kernel<<<(n + 3) / 4, 256, 0, stream>>>(x, csr, offsets, dinv,
                                                   nullptr, nullptr, bufA, n);
    // out1 = prelu(aggx @ W1 + b1) -> d_out as [n,256]   (K=128, N=256)
    gemmL_kernel<4, 16><<<256, 512, 0, stream>>>(bufA, W1t_hi, W1t_lo, out1,
                                                 n, ntiles, b1, 2, a_ptr);

    // ---- layer 2: g2 = out1 @ W2 -> bufA [n,128]   (K=256, N=128, one pass)
    gemmL_kernel<8, 8><<<256, 512, 0, stream>>>(out1, W2t_hi, W2t_lo, bufA,
                                                n, ntiles, nullptr, 0, nullptr);
    // out = prelu(A_hat agg of bufA + b2) -> d_out[0 : n*128]
    agg128_kernel<<<(n + 3) / 4, 256, 0, stream>>>(bufA, csr, offsets, dinv,
                                                   b2, a_ptr, out_final, n);

    // ---- MLP head (K=128, N=128; 64KB LDS -> 2 blocks/CU) ----
    gemmL_kernel<4, 8><<<512, 512, 0, stream>>>(out_final, f1t_hi, f1t_lo, bufA,
                                                n, ntiles, fc1_b, 1, nullptr);
    gemmL_kernel<4, 8><<<512, 512, 0, stream>>>(bufA, f2t_hi, f2t_lo, proj_final,
                                                n, ntiles, fc2_b, 0, nullptr);
}

// Round 6
// 798.875 us; speedup vs baseline: 1.4648x; 1.4648x over previous
//
#include <hip/hip_runtime.h>

// GCN: out = prelu(GCNConv2(prelu(GCNConv1(x)))), proj = MLP(out)
// R5: agg128 edge loop unrolled 12-wide (latency -> 12 gathers in flight).
// R8: weights fragment-contiguous; operand-swapped MFMA; coalesced C stores.
// R9 (reverted): full-B-in-LDS collapsed occupancy (1 blk/CU, 2 waves/SIMD).
// R10: PRE-SPLIT A at producers. agg/gemm epilogues emit bf16 hi/lo planes
//      (same split1 of same fp32 -> bit-identical). GEMM inner loop = pure
//      short8 load + MFMA (split-VALU gone, A bytes halved, intermediate
//      round-trips halved). GEMM grid 1D cols-inner so blocks sharing A rows
//      are temporally adjacent (A fits L3 -> re-reads dedupe off-HBM).
//      Plane buffers carved from d_out/bufA (timeline-checked, no new ws).

typedef __attribute__((ext_vector_type(4))) float  f32x4;
typedef __attribute__((ext_vector_type(8))) __bf16 bf16x8;
typedef __attribute__((ext_vector_type(8))) short  short8;

__device__ __forceinline__ bf16x8 as_bf(short8 s) {
    union { short8 s; bf16x8 b; } u; u.s = s; return u.b;
}

// truncation split: x = hi + lo + eps, |eps| <= 2^-16 |x|
__device__ __forceinline__ short2 split1(float x) {
    unsigned u = __float_as_uint(x);
    short hi = (short)(u >> 16);
    float hif = __uint_as_float(u & 0xFFFF0000u);
    short lo = (short)(__float_as_uint(x - hif) >> 16);
    return make_short2(hi, lo);
}

__device__ __forceinline__ unsigned pack2(short a, short b) {
    return ((unsigned)(unsigned short)a) | ((unsigned)(unsigned short)b << 16);
}

// ---------------- degree count ----------------
__global__ void deg_kernel(const int* __restrict__ dst, int* __restrict__ deg, int E) {
    int e = blockIdx.x * blockDim.x + threadIdx.x;
    if (e < E) atomicAdd(&deg[dst[e]], 1);
}

// ---------------- scan phase 1: per-block (1024 elems) sum + dinv ----------------
__global__ __launch_bounds__(256)
void part_kernel(const int* __restrict__ deg, int* __restrict__ bsum,
                 float* __restrict__ dinv, int n) {
    int tid = threadIdx.x;
    int base = blockIdx.x * 1024 + tid * 4;
    int d[4] = {0, 0, 0, 0};
    if (base + 3 < n) {
        int4 v = *(const int4*)(deg + base);
        d[0] = v.x; d[1] = v.y; d[2] = v.z; d[3] = v.w;
    } else {
        for (int j = 0; j < 4; ++j) if (base + j < n) d[j] = deg[base + j];
    }
    for (int j = 0; j < 4; ++j)
        if (base + j < n) dinv[base + j] = rsqrtf((float)(d[j] + 1));
    int s = d[0] + d[1] + d[2] + d[3];
    for (int off = 32; off > 0; off >>= 1) s += __shfl_down(s, off);
    __shared__ int wsum[4];
    if ((tid & 63) == 0) wsum[tid >> 6] = s;
    __syncthreads();
    if (tid == 0) bsum[blockIdx.x] = wsum[0] + wsum[1] + wsum[2] + wsum[3];
}

// ---------------- scan phase 2: single block over block sums ----------------
__global__ __launch_bounds__(1024)
void topscan_kernel(const int* __restrict__ bsum, int* __restrict__ bbase, int nb) {
    __shared__ int sh[1024];
    int tid = threadIdx.x;
    int own = (tid < nb) ? bsum[tid] : 0;
    sh[tid] = own;
    __syncthreads();
    for (int off = 1; off < 1024; off <<= 1) {
        int t = (tid >= off) ? sh[tid - off] : 0;
        __syncthreads();
        sh[tid] += t;
        __syncthreads();
    }
    if (tid < nb) bbase[tid] = sh[tid] - own;   // exclusive
}

// ---------------- scan phase 3: per-block local scan + base -> offsets ----------------
__global__ __launch_bounds__(256)
void offs_kernel(const int* __restrict__ deg, const int* __restrict__ bbase,
                 int* __restrict__ offsets, int n) {
    int tid = threadIdx.x;
    int base = blockIdx.x * 1024 + tid * 4;
    int d[4] = {0, 0, 0, 0};
    if (base + 3 < n) {
        int4 v = *(const int4*)(deg + base);
        d[0] = v.x; d[1] = v.y; d[2] = v.z; d[3] = v.w;
    } else {
        for (int j = 0; j < 4; ++j) if (base + j < n) d[j] = deg[base + j];
    }
    int s = d[0] + d[1] + d[2] + d[3];
    __shared__ int sh[256];
    sh[tid] = s;
    __syncthreads();
    for (int off = 1; off < 256; off <<= 1) {
        int t = (tid >= off) ? sh[tid - off] : 0;
        __syncthreads();
        sh[tid] += t;
        __syncthreads();
    }
    int run = bbase[blockIdx.x] + sh[tid] - s;   // exclusive prefix for this thread
    for (int j = 0; j < 4; ++j) {
        int idx = base + j;
        if (idx <= n) offsets[idx] = run;        // also writes offsets[n]
        if (idx < n) run += d[j];
    }
}

// ---------------- CSR fill ----------------
__global__ void fill_kernel(const int* __restrict__ src, const int* __restrict__ dst,
                            const int* __restrict__ offsets, int* __restrict__ cursor,
                            int* __restrict__ csr, int E) {
    int e = blockIdx.x * blockDim.x + threadIdx.x;
    if (e < E) {
        int d = dst[e];
        int pos = offsets[d] + atomicAdd(&cursor[d], 1);
        csr[pos] = src[e];
    }
}

// ---- weight convert: W[K][N] fp32 -> fragment-contiguous bf16 hi/lo planes ----
// elem o = ((nt*KT + kt)*64 + quad*16 + l16)*8 + j  <->  col nt*16+l16,
// k = kt*32 + quad*8 + j. Wave frag load = one contiguous 1KB block.
__global__ void wconv_kernel(const float* __restrict__ W, short* __restrict__ Fh,
                             short* __restrict__ Fl, int K, int N, int ktlog) {
    int o = blockIdx.x * blockDim.x + threadIdx.x;
    if (o >= K * N) return;
    int j  = o & 7;
    int l  = (o >> 3) & 15;
    int q  = (o >> 7) & 3;
    int t2 = o >> 9;
    int kt = t2 & ((1 << ktlog) - 1);
    int nt = t2 >> ktlog;
    int nn = nt * 16 + l;
    int kk = kt * 32 + q * 8 + j;
    short2 s = split1(W[(size_t)kk * N + nn]);
    Fh[o] = s.x;
    Fl[o] = s.y;
}

// ---------------- aggregation over dim-128 rows, 1 wave per node ----------------
// acc = dinv[v]*(dinv[v]*g[v] + sum dinv[s]*g[s]) (+bias, prelu if bias).
// Outputs: optional fp32 row (outf) and/or bf16 hi/lo planes (oh/ol) for the
// downstream GEMM (split1 of the same register value -> bit-identical).
__global__ __launch_bounds__(256)
void agg128_kernel(const float* __restrict__ g, const int* __restrict__ csr,
                   const int* __restrict__ offsets, const float* __restrict__ dinv,
                   const float* __restrict__ bias, const float* __restrict__ a_ptr,
                   float* __restrict__ outf, short* __restrict__ oh,
                   short* __restrict__ ol, int n) {
    int w = threadIdx.x >> 6;
    int lane = threadIdx.x & 63;
    int v = blockIdx.x * 4 + w;
    if (v >= n) return;
    const char* gb = (const char*)g;          // 32-bit voffset form (51.2 MB buffer)
    unsigned loff = (unsigned)lane * 8u;
    float dv = dinv[v];
    float2 self = *(const float2*)(gb + ((unsigned)v * 512u + loff));
    float accx = dv * self.x;
    float accy = dv * self.y;
    int e = offsets[v], end = offsets[v + 1];
#pragma unroll 1
    for (; e < end; e += 12) {
        int   idx[12];
        float dd[12];
        float2 mm[12];
#pragma unroll
        for (int j = 0; j < 12; ++j) {
            int ee = e + j;
            idx[j] = csr[ee < end ? ee : end - 1];   // clamped dup -> cache hit
        }
#pragma unroll
        for (int j = 0; j < 12; ++j)
            dd[j] = (e + j < end) ? dinv[idx[j]] : 0.f;
#pragma unroll
        for (int j = 0; j < 12; ++j)
            mm[j] = *(const float2*)(gb + ((unsigned)idx[j] * 512u + loff));
#pragma unroll
        for (int j = 0; j < 12; ++j) {
            accx += dd[j] * mm[j].x;
            accy += dd[j] * mm[j].y;
        }
    }
    accx *= dv;
    accy *= dv;
    if (bias) {
        float a = *a_ptr;
        float2 bb = ((const float2*)bias)[lane];
        accx += bb.x;
        accy += bb.y;
        accx = accx >= 0.f ? accx : a * accx;
        accy = accy >= 0.f ? accy : a * accy;
    }
    if (outf) {
        float2 r; r.x = accx; r.y = accy;
        ((float2*)outf)[(size_t)v * 64 + lane] = r;
    }
    if (oh) {
        short2 s0 = split1(accx), s1 = split1(accy);
        ((unsigned*)(oh + (size_t)v * 128))[lane] = pack2(s0.x, s1.x);
        ((unsigned*)(ol + (size_t)v * 128))[lane] = pack2(s0.y, s1.y);
    }
}

// ---------------- split-bf16 MFMA GEMM, pre-split A planes ----------------
// C = epi( A @ B + bias ); A given as bf16 hi/lo planes [M][K=KT*32].
// Inner loop is pure short8-load + MFMA (no split VALU). B frags (T*KT*2,
// frag-contiguous 1KB wave loads) register-resident; tpb row-tiles per block.
// 1D grid, cols-inner: bid = rowblk*ncol + colblk -> blocks sharing A rows
// are temporally adjacent (A fits L3). EPI: 0 = fp32 float4 stores,
// 1 = split bf16 hi/lo plane stores (post-activation, split1-identical).
// act: 0=none, 1=relu, 2=prelu(a).
template<int KT, int T, int EPI>
__global__ __launch_bounds__(256)
void gemm64_kernel(const short* __restrict__ Ah, const short* __restrict__ Al,
                   const short* __restrict__ Bh, const short* __restrict__ Bl,
                   float* __restrict__ Cf, short* __restrict__ Ch,
                   short* __restrict__ Cl, int M, int N, int ncol,
                   int mtiles, int tpb,
                   const float* __restrict__ bias, int act,
                   const float* __restrict__ a_ptr) {
    constexpr int K = KT * 32;
    const int tid  = threadIdx.x;
    const int wave = tid >> 6, lane = tid & 63;
    const int quad = lane >> 4, l16 = lane & 15;
    const int bid  = blockIdx.x;
    const int rowblk = bid / ncol;
    const int colblk = bid - rowblk * ncol;
    const int col0 = colblk * (T * 16);
    const int nt0  = col0 >> 4;

    // B fragments, register-resident for the whole block lifetime.
    bf16x8 bf[T][KT][2];
#pragma unroll
    for (int t = 0; t < T; ++t)
#pragma unroll
        for (int kt = 0; kt < KT; ++kt) {
            size_t off = ((size_t)((nt0 + t) * KT + kt) << 9) + (lane << 3);
            bf[t][kt][0] = as_bf(*(const short8*)(Bh + off));
            bf[t][kt][1] = as_bf(*(const short8*)(Bl + off));
        }

    const float aw = (act == 2) ? *a_ptr : 0.f;

    const int t0 = rowblk * tpb;
    const int t1 = (t0 + tpb < mtiles) ? t0 + tpb : mtiles;
#pragma unroll 1
    for (int tile = t0; tile < t1; ++tile) {
        const int m  = tile * 64 + wave * 16 + l16;
        const int mc = m < M ? m : M - 1;
        const short* Ahp = Ah + (size_t)mc * K + quad * 8;
        const short* Alp = Al + (size_t)mc * K + quad * 8;

        short8 ahv[KT], alv[KT];
#pragma unroll
        for (int kt = 0; kt < KT; ++kt) {
            ahv[kt] = *(const short8*)(Ahp + kt * 32);
            alv[kt] = *(const short8*)(Alp + kt * 32);
        }

        f32x4 acc[T];
#pragma unroll
        for (int t = 0; t < T; ++t) acc[t] = (f32x4){0.f, 0.f, 0.f, 0.f};

#pragma unroll
        for (int kt = 0; kt < KT; ++kt) {
            bf16x8 a_hi = as_bf(ahv[kt]), a_lo = as_bf(alv[kt]);
#pragma unroll
            for (int t = 0; t < T; ++t) {
                acc[t] = __builtin_amdgcn_mfma_f32_16x16x32_bf16(bf[t][kt][0], a_hi, acc[t], 0, 0, 0);
                acc[t] = __builtin_amdgcn_mfma_f32_16x16x32_bf16(bf[t][kt][1], a_hi, acc[t], 0, 0, 0);
                acc[t] = __builtin_amdgcn_mfma_f32_16x16x32_bf16(bf[t][kt][0], a_lo, acc[t], 0, 0, 0);
            }
        }

        if (m < M) {
#pragma unroll
            for (int t = 0; t < T; ++t) {
                const int col = col0 + t * 16 + quad * 4;
                float4 v;
                v.x = acc[t][0]; v.y = acc[t][1]; v.z = acc[t][2]; v.w = acc[t][3];
                if (bias) {
                    const float4 bb = *(const float4*)(bias + col);
                    v.x += bb.x; v.y += bb.y; v.z += bb.z; v.w += bb.w;
                }
                if (act == 1) {
                    v.x = fmaxf(v.x, 0.f); v.y = fmaxf(v.y, 0.f);
                    v.z = fmaxf(v.z, 0.f); v.w = fmaxf(v.w, 0.f);
                } else if (act == 2) {
                    v.x = v.x >= 0.f ? v.x : aw * v.x;
                    v.y = v.y >= 0.f ? v.y : aw * v.y;
                    v.z = v.z >= 0.f ? v.z : aw * v.z;
                    v.w = v.w >= 0.f ? v.w : aw * v.w;
                }
                if (EPI == 0) {
                    *(float4*)(Cf + (size_t)m * N + col) = v;
                } else {
                    short2 s0 = split1(v.x), s1 = split1(v.y);
                    short2 s2 = split1(v.z), s3 = split1(v.w);
                    uint2 hp, lp;
                    hp.x = pack2(s0.x, s1.x); hp.y = pack2(s2.x, s3.x);
                    lp.x = pack2(s0.y, s1.y); lp.y = pack2(s2.y, s3.y);
                    *(uint2*)(Ch + (size_t)m * N + col) = hp;
                    *(uint2*)(Cl + (size_t)m * N + col) = lp;
                }
            }
        }
    }
}

extern "C" void kernel_launch(void* const* d_in, const int* in_sizes, int n_in,
                              void* d_out, int out_size, void* d_ws, size_t ws_size,
                              hipStream_t stream) {
    const float* x     = (const float*)d_in[0];
    const int*   ei    = (const int*)d_in[1];   // harness materializes int64 as int32
    const float* W1    = (const float*)d_in[2];
    const float* b1    = (const float*)d_in[3];
    const float* W2    = (const float*)d_in[4];
    const float* b2    = (const float*)d_in[5];
    const float* a_ptr = (const float*)d_in[6];
    const float* fc1_w = (const float*)d_in[7];
    const float* fc1_b = (const float*)d_in[8];
    const float* fc2_w = (const float*)d_in[9];
    const float* fc2_b = (const float*)d_in[10];

    const int n = in_sizes[0] / 128;
    const int E = in_sizes[1] / 2;
    const int* src = ei;
    const int* dst = ei + E;
    const int nb = (n + 1023) >> 10;            // scan blocks (98 for n=100000)

    float* out_final  = (float*)d_out;                    // [n,128]
    float* proj_final = out_final + (size_t)n * 128;      // [n,128]

    // Plane aliases (timeline-checked):
    //  agg1 planes   -> bufA region           (consumed by W1)
    //  out1 planes   -> d_out (both halves)   (W1 -> W2, dead after W2)
    //  agg2 planes   -> proj region           (consumed by fc1, overwritten by fc2)
    //  fc1 planes    -> bufA region           (consumed by fc2)

    // workspace carve-out (~59.6 MB total)
    char* p = (char*)d_ws;
    auto take = [&](size_t bytes) -> char* {
        char* q = p;
        p += (bytes + 1023) & ~(size_t)1023;
        return q;
    };
    int*   deg     = (int*)take((size_t)n * 4);
    int*   offsets = (int*)take(((size_t)n + 1) * 4);
    int*   cursor  = (int*)take((size_t)n * 4);
    float* dinv    = (float*)take((size_t)n * 4);
    int*   bsum    = (int*)take((size_t)1024 * 4);
    int*   bbase   = (int*)take((size_t)1024 * 4);
    int*   csr     = (int*)take((size_t)E * 4);
    short* W1t_hi  = (short*)take((size_t)256 * 128 * 2);
    short* W1t_lo  = (short*)take((size_t)256 * 128 * 2);
    short* W2t_hi  = (short*)take((size_t)128 * 256 * 2);
    short* W2t_lo  = (short*)take((size_t)128 * 256 * 2);
    short* f1t_hi  = (short*)take((size_t)128 * 128 * 2);
    short* f1t_lo  = (short*)take((size_t)128 * 128 * 2);
    short* f2t_hi  = (short*)take((size_t)128 * 128 * 2);
    short* f2t_lo  = (short*)take((size_t)128 * 128 * 2);
    float* bufA    = (float*)take((size_t)n * 128 * 4);   // [n,128] f32 scratch

    short* A1h = (short*)bufA;                // agg1 planes [n,128] x2
    short* A1l = A1h + (size_t)n * 128;
    short* O1h = (short*)d_out;               // out1 planes [n,256] x2 (fills d_out)
    short* O1l = O1h + (size_t)n * 256;
    short* P2h = (short*)proj_final;          // agg2 planes [n,128] x2 (proj region)
    short* P2l = P2h + (size_t)n * 128;
    short* F1h = (short*)bufA;                // fc1 planes [n,128] x2
    short* F1l = F1h + (size_t)n * 128;

    (void)hipMemsetAsync(deg, 0, (size_t)n * 4, stream);
    (void)hipMemsetAsync(cursor, 0, (size_t)n * 4, stream);

    // ---- weight pre-transpose/split into fragment order (tiny) ----
    wconv_kernel<<<(128 * 256 + 255) / 256, 256, 0, stream>>>(W1, W1t_hi, W1t_lo, 128, 256, 2);
    wconv_kernel<<<(256 * 128 + 255) / 256, 256, 0, stream>>>(W2, W2t_hi, W2t_lo, 256, 128, 3);
    wconv_kernel<<<(128 * 128 + 255) / 256, 256, 0, stream>>>(fc1_w, f1t_hi, f1t_lo, 128, 128, 2);
    wconv_kernel<<<(128 * 128 + 255) / 256, 256, 0, stream>>>(fc2_w, f2t_hi, f2t_lo, 128, 128, 2);

    // ---- CSR build (shared by both conv layers) ----
    deg_kernel<<<(E + 255) / 256, 256, 0, stream>>>(dst, deg, E);
    part_kernel<<<nb, 256, 0, stream>>>(deg, bsum, dinv, n);
    topscan_kernel<<<1, 1024, 0, stream>>>(bsum, bbase, nb);
    offs_kernel<<<nb, 256, 0, stream>>>(deg, bbase, offsets, n);
    fill_kernel<<<(E + 255) / 256, 256, 0, stream>>>(src, dst, offsets, cursor, csr, E);

    const int mtiles = (n + 63) / 64;
    const int TPB = 4;
    const int RB = (mtiles + TPB - 1) / TPB;

    // ---- layer 1: aggregate first (dim 128): agg1 planes <- A_hat x
    agg128_kernel<<<(n + 3) / 4, 256, 0, stream>>>(x, csr, offsets, dinv,
                                                   nullptr, nullptr,
                                                   nullptr, A1h, A1l, n);
    // out1 planes = split(prelu(agg1 @ W1 + b1))   (K=128, N=256, 4 col-blocks)
    gemm64_kernel<4, 4, 1><<<RB * 4, 256, 0, stream>>>(
        A1h, A1l, W1t_hi, W1t_lo, nullptr, O1h, O1l,
        n, 256, 4, mtiles, TPB, b1, 2, a_ptr);

    // ---- layer 2: bufA(fp32) = out1 @ W2   (K=256, N=128, 4 col-blocks)
    gemm64_kernel<8, 2, 0><<<RB * 4, 256, 0, stream>>>(
        O1h, O1l, W2t_hi, W2t_lo, bufA, nullptr, nullptr,
        n, 128, 4, mtiles, TPB, nullptr, 0, nullptr);
    // out = prelu(A_hat agg of bufA + b2): fp32 -> d_out, planes -> proj region
    agg128_kernel<<<(n + 3) / 4, 256, 0, stream>>>(bufA, csr, offsets, dinv,
                                                   b2, a_ptr,
                                                   out_final, P2h, P2l, n);

    // ---- MLP head ----
    // fc1 planes = split(relu(out @ fc1 + fc1_b))  (K=128, N=128, 2 col-blocks)
    gemm64_kernel<4, 4, 1><<<RB * 2, 256, 0, stream>>>(
        P2h, P2l, f1t_hi, f1t_lo, nullptr, F1h, F1l,
        n, 128, 2, mtiles, TPB, fc1_b, 1, nullptr);
    // proj = fc1 @ fc2 + fc2_b (fp32 -> proj region, overwrites consumed P2 planes)
    gemm64_kernel<4, 4, 0><<<RB * 2, 256, 0, stream>>>(
        F1h, F1l, f2t_hi, f2t_lo, proj_final, nullptr, nullptr,
        n, 128, 2, mtiles, TPB, fc2_b, 0, nullptr);
}